// Round 7
// baseline (2552.389 us; speedup 1.0000x reference)
//
#include <hip/hip_runtime.h>

#define DD   128
#define NL   8000
#define NC   16000
#define TSTEPS 8
#define ROWW 96    // max clauses per literal (mean 40, std 6.3)
#define COLW 64    // max literals per clause (mean 20, std 4.4)
#define NBLK 256   // persistent grid: 256 blocks <= 256 CUs -> co-residency by capacity
#define CTILES (NC / 32)   // 500 clause tiles (32 rows)
#define LTILES (NL / 16)   // 500 literal tiles (16 rows)

// clause LDS: 32 octs x 32 rows, stride 33 short8 (pad kills staging conflicts)
#define CSTR 33
#define CSPL (32 * CSTR * 8)   // shorts per split = 8448
// literal LDS: 48 octs x 16 rows, stride 17 short8
#define LSTR 17
#define LSPL (48 * LSTR * 8)   // shorts per split = 6528

typedef __attribute__((ext_vector_type(8))) short short8;
typedef __attribute__((ext_vector_type(4))) float f32x4;

__device__ __forceinline__ float frcp(float x) { return __builtin_amdgcn_rcpf(x); }
__device__ __forceinline__ float sigm(float x) { return frcp(1.f + __expf(-x)); }
__device__ __forceinline__ float tanh_(float x) {
  float e = __expf(2.f * x);
  return 1.f - 2.f * frcp(e + 1.f);
}
__device__ __forceinline__ void add4(float4& a, const float4 b) {
  a.x += b.x; a.y += b.y; a.z += b.z; a.w += b.w;
}
__device__ __forceinline__ unsigned short bfround(float v) {  // RNE fp32 -> bf16
  unsigned u = __float_as_uint(v);
  return (unsigned short)((u + 0x7FFF + ((u >> 16) & 1)) >> 16);
}
__device__ __forceinline__ float bf2f(unsigned short b) {
  return __uint_as_float(((unsigned)b) << 16);
}
__device__ __forceinline__ int4 packi4(const unsigned short* p) {
  return make_int4(p[0] | ((int)p[1] << 16), p[2] | ((int)p[3] << 16),
                   p[4] | ((int)p[5] << 16), p[6] | ((int)p[7] << 16));
}

// triple-split 8 floats -> 3 bf16 octets, clause layout (stride CSTR, splits CSPL)
__device__ __forceinline__ void store_oct3C(unsigned short* A, int oct, int m,
                                            float4 a, float4 b) {
  float f[8] = {a.x, a.y, a.z, a.w, b.x, b.y, b.z, b.w};
  unsigned short h[8], md[8], lo[8];
  #pragma unroll
  for (int j = 0; j < 8; ++j) {
    h[j] = bfround(f[j]);
    float r1 = f[j] - bf2f(h[j]);       // exact (Sterbenz)
    md[j] = bfround(r1);
    float r2 = r1 - bf2f(md[j]);        // exact
    lo[j] = bfround(r2);
  }
  int base = (oct * CSTR + m) * 8;
  *(int4*)(A + base)            = packi4(h);
  *(int4*)(A + CSPL + base)     = packi4(md);
  *(int4*)(A + 2 * CSPL + base) = packi4(lo);
}

// triple-split 4 floats -> half-octet, literal layout (stride LSTR, splits LSPL)
__device__ __forceinline__ void store_half3L(unsigned short* A, int oct, int half, int m,
                                             float4 a) {
  float f[4] = {a.x, a.y, a.z, a.w};
  unsigned short h[4], md[4], lo[4];
  #pragma unroll
  for (int j = 0; j < 4; ++j) {
    h[j] = bfround(f[j]);
    float r1 = f[j] - bf2f(h[j]);
    md[j] = bfround(r1);
    float r2 = r1 - bf2f(md[j]);
    lo[j] = bfround(r2);
  }
  int base = (oct * LSTR + m) * 8 + half * 4;
  *(int2*)(A + base)            = make_int2(h[0]  | ((int)h[1]  << 16), h[2]  | ((int)h[3]  << 16));
  *(int2*)(A + LSPL + base)     = make_int2(md[0] | ((int)md[1] << 16), md[2] | ((int)md[3] << 16));
  *(int2*)(A + 2 * LSPL + base) = make_int2(lo[0] | ((int)lo[1] << 16), lo[2] | ((int)lo[3] << 16));
}

// 6-term triple-split product: hh + hm + mh + hl + lh + mm  (error ~2^-27)
#define MFMA6(ACC, AH, AM, AL, BH, BM, BL)                                   \
  ACC = __builtin_amdgcn_mfma_f32_16x16x32_bf16(AH, BH, ACC, 0, 0, 0);       \
  ACC = __builtin_amdgcn_mfma_f32_16x16x32_bf16(AH, BM, ACC, 0, 0, 0);       \
  ACC = __builtin_amdgcn_mfma_f32_16x16x32_bf16(AM, BH, ACC, 0, 0, 0);       \
  ACC = __builtin_amdgcn_mfma_f32_16x16x32_bf16(AH, BL, ACC, 0, 0, 0);       \
  ACC = __builtin_amdgcn_mfma_f32_16x16x32_bf16(AL, BH, ACC, 0, 0, 0);       \
  ACC = __builtin_amdgcn_mfma_f32_16x16x32_bf16(AM, BM, ACC, 0, 0, 0);

// ---------------- preprocessing ----------------

// one pass over M (512 MB): padded-ELL both directions
__global__ __launch_bounds__(256) void scan_M(const float4* __restrict__ M4,
                                              int* __restrict__ csr, int* __restrict__ csc,
                                              int* __restrict__ rcnt, int* __restrict__ ccnt) {
  const int total = (NL * NC) / 4;
  int stride = gridDim.x * blockDim.x;
  for (int i = blockIdx.x * blockDim.x + threadIdx.x; i < total; i += stride) {
    float4 v = M4[i];
    if (v.x == 0.f && v.y == 0.f && v.z == 0.f && v.w == 0.f) continue;
    int base = i * 4;
    int l = base / NC;
    int c0 = base - l * NC;
    float vv[4] = {v.x, v.y, v.z, v.w};
    #pragma unroll
    for (int e = 0; e < 4; ++e) {
      if (vv[e] != 0.f) {
        int c = c0 + e;
        int rp = atomicAdd(&rcnt[l], 1);
        if (rp < ROWW) csr[l * ROWW + rp] = c;
        int cp = atomicAdd(&ccnt[c], 1);
        if (cp < COLW) csc[c * COLW + cp] = l;
      }
    }
  }
}

__device__ __forceinline__ void split_store(float w, int idx, unsigned short* hi,
                                            unsigned short* md, unsigned short* lo) {
  unsigned short h = bfround(w);
  float r1 = w - bf2f(h);
  unsigned short m = bfround(r1);
  float r2 = r1 - bf2f(m);
  hi[idx] = h; md[idx] = m; lo[idx] = bfround(r2);
}

// combined clause weights B[k][n]: k<128: sum_d WihC[n,d]*Wlc[d,k]; k>=128: WhhC[n,k-128]
__global__ __launch_bounds__(256) void build_packC(
    const float* __restrict__ WihC, const float* __restrict__ Wlc, const float* __restrict__ WhhC,
    unsigned short* __restrict__ pkhi, unsigned short* __restrict__ pkmd, unsigned short* __restrict__ pklo) {
  int i = blockIdx.x * 256 + threadIdx.x;   // [0, 256*512)
  int k = i >> 9, n = i & 511;
  float w;
  if (k < 128) {
    float s = 0.f;
    for (int d = 0; d < 128; ++d) s += WihC[n * 128 + d] * Wlc[d * 128 + k];
    w = s;
  } else {
    w = WhhC[n * 128 + (k - 128)];
  }
  split_store(w, ((k >> 3) * 512 + n) * 8 + (k & 7), pkhi, pkmd, pklo);
}

// literal B[k][n]: k<128: sum_d WihL[n,d]*Wcl[d,k]; 128..255: WihL[n,k]; 256..383: WhhL[n,k-256]
__global__ __launch_bounds__(256) void build_packL(
    const float* __restrict__ WihL, const float* __restrict__ Wcl, const float* __restrict__ WhhL,
    unsigned short* __restrict__ pkhi, unsigned short* __restrict__ pkmd, unsigned short* __restrict__ pklo) {
  int i = blockIdx.x * 256 + threadIdx.x;   // [0, 384*512)
  int k = i >> 9, n = i & 511;
  float w;
  if (k < 128) {
    float s = 0.f;
    for (int d = 0; d < 128; ++d) s += WihL[n * 256 + d] * Wcl[d * 128 + k];
    w = s;
  } else if (k < 256) {
    w = WihL[n * 256 + k];
  } else {
    w = WhhL[n * 128 + (k - 256)];
  }
  split_store(w, ((k >> 3) * 512 + n) * 8 + (k & 7), pkhi, pkmd, pklo);
}

__global__ __launch_bounds__(256) void build_bias(
    const float* __restrict__ bihC, const float* __restrict__ bhhC,
    const float* __restrict__ WihC, const float* __restrict__ blc,
    const float* __restrict__ bihL, const float* __restrict__ bhhL,
    const float* __restrict__ WihL, const float* __restrict__ bcl,
    float* __restrict__ bsumC, float* __restrict__ bvecC,
    float* __restrict__ bsumL, float* __restrict__ bvecL) {
  int i = blockIdx.x * 256 + threadIdx.x;   // [0, 1024)
  if (i < 512) {
    bsumC[i] = bihC[i] + bhhC[i];
    float s = 0.f;
    for (int d = 0; d < 128; ++d) s += WihC[i * 128 + d] * blc[d];
    bvecC[i] = s;
  } else if (i < 1024) {
    int n = i - 512;
    bsumL[n] = bihL[n] + bhhL[n];
    float s = 0.f;
    for (int d = 0; d < 128; ++d) s += WihL[n * 256 + d] * bcl[d];
    bvecL[n] = s;
  }
}

// ---------------- manual grid barrier (monotone counter, device scope) ----------------
// 256 blocks <= 256 CUs: all blocks resident by capacity -> no deadlock.
// Release: __threadfence + ACQ_REL fetch_add; Acquire: AGENT-scope load + __threadfence.
__device__ __forceinline__ void grid_barrier(int* cnt, int& gen) {
  __syncthreads();
  if (threadIdx.x == 0) {
    __threadfence();
    ++gen;
    __hip_atomic_fetch_add(cnt, 1, __ATOMIC_ACQ_REL, __HIP_MEMORY_SCOPE_AGENT);
    while (__hip_atomic_load(cnt, __ATOMIC_ACQUIRE, __HIP_MEMORY_SCOPE_AGENT) < gen * NBLK)
      __builtin_amdgcn_s_sleep(1);
    __threadfence();
  }
  __syncthreads();
}

// ---------------- persistent fused step kernel ----------------
// 256 blocks x 512 threads (8 waves). Per step: clause tiles (500 x 32 rows,
// stride-256 loop), grid barrier, literal tiles (500 x 16 rows), grid barrier.

__global__ __launch_bounds__(512, 4) void fused_steps(
    const float* __restrict__ L0, const float* __restrict__ hL0, const float* __restrict__ hC0,
    const int* __restrict__ csr, const int* __restrict__ csc,
    const int* __restrict__ rcnt, const int* __restrict__ ccnt,
    const unsigned short* __restrict__ pkChi, const unsigned short* __restrict__ pkCmd,
    const unsigned short* __restrict__ pkClo,
    const unsigned short* __restrict__ pkLhi, const unsigned short* __restrict__ pkLmd,
    const unsigned short* __restrict__ pkLlo,
    const float* __restrict__ bsumC, const float* __restrict__ bvecC,
    const float* __restrict__ bsumL, const float* __restrict__ bvecL,
    float* __restrict__ hL, float* __restrict__ hC, float* __restrict__ Cs,
    float* __restrict__ Lbuf, int* __restrict__ bar) {
  __shared__ unsigned short A[3 * CSPL];   // 50,688 B (literal tiles use first 39,168 B)

  const int t = threadIdx.x;
  const int b = blockIdx.x;
  const int w = t >> 6, l = t & 63;
  const int quad = l >> 4, lane16 = l & 15;
  const int cw = w * 16 + lane16;   // output col 0..127 owned by this lane
  int gen = 0;

  { // prologue: init state from inputs (grid-stride f4 copies)
    int gid = b * 512 + t, gstr = NBLK * 512;
    for (int i = gid; i < NL * DD / 4; i += gstr) ((float4*)Lbuf)[i] = ((const float4*)L0)[i];
    for (int i = gid; i < NL * DD / 4; i += gstr) ((float4*)hL)[i]   = ((const float4*)hL0)[i];
    for (int i = gid; i < NC * DD / 4; i += gstr) ((float4*)hC)[i]   = ((const float4*)hC0)[i];
  }

  for (int step = 0; step < TSTEPS; ++step) {
    grid_barrier(bar, gen);   // prologue / previous literal phase visible

    // ---- clause phase ----
    for (int tile = b; tile < CTILES; tile += NBLK) {
      const int rowBase = tile * 32;
      { // stage A: K = [msgs(128)=oct 0..15 | hC(128)=oct 16..31]
        const int r = t >> 4, sub = t & 15;
        const int c = rowBase + r;
        int cnt = ccnt[c]; int cl2 = cnt > COLW ? COLW : cnt;
        const int* lst = csc + c * COLW;
        float4 a0 = make_float4(0, 0, 0, 0), a1 = a0;
        for (int j = 0; j < cl2; ++j) {
          const float4* s4 = (const float4*)(Lbuf + (size_t)lst[j] * DD + sub * 8);
          add4(a0, s4[0]); add4(a1, s4[1]);
        }
        store_oct3C(A, sub, r, a0, a1);
        const float4* h4 = (const float4*)(hC + (size_t)c * DD + sub * 8);
        store_oct3C(A, 16 + sub, r, h4[0], h4[1]);
      }
      __syncthreads();

      f32x4 acc[2][4];
      #pragma unroll
      for (int mt = 0; mt < 2; ++mt)
        #pragma unroll
        for (int g = 0; g < 4; ++g) acc[mt][g] = (f32x4){0.f, 0.f, 0.f, 0.f};

      const short8* As = (const short8*)A;        // idx = oct*CSTR + m
      const short8* Bh = (const short8*)pkChi;    // idx = oct*512 + n
      const short8* Bm = (const short8*)pkCmd;
      const short8* Bl = (const short8*)pkClo;

      #pragma unroll 2
      for (int s = 0; s < 8; ++s) {               // K=256
        int ao = (s * 4 + quad) * CSTR + lane16;
        short8 a0h = As[ao],                   a1h = As[ao + 16];
        short8 a0m = As[CSPL / 8 + ao],        a1m = As[CSPL / 8 + ao + 16];
        short8 a0l = As[2 * (CSPL / 8) + ao],  a1l = As[2 * (CSPL / 8) + ao + 16];
        int bo = (s * 4 + quad) * 512 + cw;
        #pragma unroll
        for (int g = 0; g < 4; ++g) {
          short8 bh = Bh[bo + g * 128];
          short8 bm = Bm[bo + g * 128];
          short8 bl = Bl[bo + g * 128];
          MFMA6(acc[0][g], a0h, a0m, a0l, bh, bm, bl);
          MFMA6(acc[1][g], a1h, a1m, a1l, bh, bm, bl);
        }
      }

      float bs_[4], bv_[4];
      #pragma unroll
      for (int g = 0; g < 4; ++g) { bs_[g] = bsumC[g * 128 + cw]; bv_[g] = bvecC[g * 128 + cw]; }
      #pragma unroll
      for (int mt = 0; mt < 2; ++mt) {
        #pragma unroll
        for (int reg = 0; reg < 4; ++reg) {
          int row = rowBase + mt * 16 + quad * 4 + reg;
          float deg = (float)ccnt[row];
          float co = hC[(size_t)row * DD + cw];
          float iv = acc[mt][0][reg] + bs_[0] + deg * bv_[0];
          float fv = acc[mt][1][reg] + bs_[1] + deg * bv_[1];
          float gv = acc[mt][2][reg] + bs_[2] + deg * bv_[2];
          float ov = acc[mt][3][reg] + bs_[3] + deg * bv_[3];
          float cn = sigm(fv) * co + sigm(iv) * tanh_(gv);
          hC[(size_t)row * DD + cw] = cn;
          Cs[(size_t)row * DD + cw] = sigm(ov) * tanh_(cn);
        }
      }
      __syncthreads();   // LDS reads done before next tile's staging
    }

    grid_barrier(bar, gen);   // Cs visible to all blocks

    // ---- literal phase: 16-row tiles, single-phase K=384 ----
    for (int tile = b; tile < LTILES; tile += NBLK) {
      const int rowBase = tile * 16;
      { // stage A: 32 threads/row, 1 float4 each; K = [msgs | L | hL]
        const int r = t >> 5, cg2 = t & 31;
        const int lr = rowBase + r;
        int cnt = rcnt[lr]; int cl2 = cnt > ROWW ? ROWW : cnt;
        const int* lst = csr + lr * ROWW;
        float4 a0 = make_float4(0, 0, 0, 0);
        for (int j = 0; j < cl2; ++j)
          add4(a0, ((const float4*)(Cs + (size_t)lst[j] * DD))[cg2]);
        store_half3L(A, cg2 >> 1, cg2 & 1, r, a0);
        store_half3L(A, 16 + (cg2 >> 1), cg2 & 1, r,
                     ((const float4*)(Lbuf + (size_t)lr * DD))[cg2]);
        store_half3L(A, 32 + (cg2 >> 1), cg2 & 1, r,
                     ((const float4*)(hL + (size_t)lr * DD))[cg2]);
      }
      __syncthreads();

      f32x4 acc[4];
      #pragma unroll
      for (int g = 0; g < 4; ++g) acc[g] = (f32x4){0.f, 0.f, 0.f, 0.f};

      const short8* As = (const short8*)A;        // idx = oct*LSTR + m
      const short8* Bh = (const short8*)pkLhi;
      const short8* Bm = (const short8*)pkLmd;
      const short8* Bl = (const short8*)pkLlo;

      #pragma unroll 2
      for (int s = 0; s < 12; ++s) {              // K=384
        int ao = (s * 4 + quad) * LSTR + lane16;
        short8 ah = As[ao];
        short8 am = As[LSPL / 8 + ao];
        short8 al = As[2 * (LSPL / 8) + ao];
        int bo = (s * 4 + quad) * 512 + cw;
        #pragma unroll
        for (int g = 0; g < 4; ++g) {
          short8 bh = Bh[bo + g * 128];
          short8 bm = Bm[bo + g * 128];
          short8 bl = Bl[bo + g * 128];
          MFMA6(acc[g], ah, am, al, bh, bm, bl);
        }
      }

      float bs_[4], bv_[4];
      #pragma unroll
      for (int g = 0; g < 4; ++g) { bs_[g] = bsumL[g * 128 + cw]; bv_[g] = bvecL[g * 128 + cw]; }
      #pragma unroll
      for (int reg = 0; reg < 4; ++reg) {
        int row = rowBase + quad * 4 + reg;
        float deg = (float)rcnt[row];
        float co = hL[(size_t)row * DD + cw];
        float iv = acc[0][reg] + bs_[0] + deg * bv_[0];
        float fv = acc[1][reg] + bs_[1] + deg * bv_[1];
        float gv = acc[2][reg] + bs_[2] + deg * bv_[2];
        float ov = acc[3][reg] + bs_[3] + deg * bv_[3];
        float cn = sigm(fv) * co + sigm(iv) * tanh_(gv);
        hL[(size_t)row * DD + cw] = cn;
        Lbuf[(size_t)row * DD + cw] = sigm(ov) * tanh_(cn);
      }
      __syncthreads();   // LDS reads done before next tile's staging
    }
  }
}

// ---------------- launch ----------------

extern "C" void kernel_launch(void* const* d_in, const int* in_sizes, int n_in,
                              void* d_out, int out_size, void* d_ws, size_t ws_size,
                              hipStream_t stream) {
  const float* L0   = (const float*)d_in[0];
  // d_in[1] = C_state (unused), d_in[5] = n_vars (flip is identity)
  const float* hL0  = (const float*)d_in[2];
  const float* hC0  = (const float*)d_in[3];
  const float* M    = (const float*)d_in[4];
  const float* Wlc  = (const float*)d_in[6];
  const float* blc  = (const float*)d_in[7];
  const float* Wcl  = (const float*)d_in[8];
  const float* bcl  = (const float*)d_in[9];
  const float* WihC = (const float*)d_in[10];
  const float* WhhC = (const float*)d_in[11];
  const float* bihC = (const float*)d_in[12];
  const float* bhhC = (const float*)d_in[13];
  const float* WihL = (const float*)d_in[14];
  const float* WhhL = (const float*)d_in[15];
  const float* bihL = (const float*)d_in[16];
  const float* bhhL = (const float*)d_in[17];

  float* ws    = (float*)d_ws;
  float* hL    = ws;                         // NL*DD
  float* hC    = hL + NL * DD;               // NC*DD
  float* Cs    = hC + NC * DD;               // NC*DD
  float* bsumC = Cs + NC * DD;               // 512 each
  float* bvecC = bsumC + 512;
  float* bsumL = bvecC + 512;
  float* bvecL = bsumL + 512;
  unsigned short* pkChi = (unsigned short*)(bvecL + 512);   // 256*512 each
  unsigned short* pkCmd = pkChi + 256 * 512;
  unsigned short* pkClo = pkCmd + 256 * 512;
  unsigned short* pkLhi = pkClo + 256 * 512;                // 384*512 each
  unsigned short* pkLmd = pkLhi + 384 * 512;
  unsigned short* pkLlo = pkLmd + 384 * 512;
  int* csr  = (int*)(pkLlo + 384 * 512);     // NL*ROWW
  int* csc  = csr + NL * ROWW;               // NC*COLW
  int* rcnt = csc + NC * COLW;               // NL
  int* ccnt = rcnt + NL;                     // NC
  int* bar  = ccnt + NC;                     // 1 (contiguous with rcnt/ccnt)
  float* Lbuf = (float*)d_out;               // literal state lives in d_out

  hipMemsetAsync(rcnt, 0, (NL + NC + 1) * sizeof(int), stream);  // rcnt, ccnt, bar

  scan_M<<<4096, 256, 0, stream>>>((const float4*)M, csr, csc, rcnt, ccnt);
  build_packC<<<(256 * 512) / 256, 256, 0, stream>>>(WihC, Wlc, WhhC, pkChi, pkCmd, pkClo);
  build_packL<<<(384 * 512) / 256, 256, 0, stream>>>(WihL, Wcl, WhhL, pkLhi, pkLmd, pkLlo);
  build_bias<<<4, 256, 0, stream>>>(bihC, bhhC, WihC, blc, bihL, bhhL, WihL, bcl,
                                    bsumC, bvecC, bsumL, bvecL);

  fused_steps<<<NBLK, 512, 0, stream>>>(
      L0, hL0, hC0, csr, csc, rcnt, ccnt,
      pkChi, pkCmd, pkClo, pkLhi, pkLmd, pkLlo,
      bsumC, bvecC, bsumL, bvecL,
      hL, hC, Cs, Lbuf, bar);
}